// Round 9
// baseline (116.570 us; speedup 1.0000x reference)
//
#include <hip/hip_runtime.h>
#include <hip/hip_bf16.h>

// Problem constants (fixed by setup_inputs)
#define BB 2
#define LL 4096
#define HH 32
#define DV 64
#define DQK 128
#define CC 64            // chunk size
#define NN 64            // number of chunks = LL/CC
#define MIMO_RANK 4.0f

typedef __attribute__((ext_vector_type(8))) short short8;
typedef __attribute__((ext_vector_type(4))) float f32x4;

__device__ __forceinline__ ushort f2bf(float f) {
    uint u = __float_as_uint(f);
    u += 0x7FFF + ((u >> 16) & 1);   // RNE
    return (ushort)(u >> 16);
}
__device__ __forceinline__ float bfbits2f(uint lo16) {
    return __uint_as_float(lo16 << 16);
}
__device__ __forceinline__ uint pkbf2(float lo, float hi) {
    return (uint)f2bf(lo) | ((uint)f2bf(hi) << 16);
}
union U8 { uint u[4]; short8 s; };

// ---- LDS swizzled-offset helpers (element offsets in ushorts) ----
// rk: [64 s][128 d], 16 slots/row, slot ^= (s&7)
__device__ __forceinline__ int rk_off(int s, int d) {
    return s * 128 + (((((d >> 3) & 15) ^ (s & 7)) << 3)) + (d & 7);
}
// rkT: [128 d][64 s], 8 slots/row, slot ^= (d&7)
__device__ __forceinline__ int rkT_off(int d, int s) {
    return d * 64 + ((((s >> 3) ^ (d & 7)) & 7) << 3) + (s & 7);
}
// uwT: [64 e][64 s], slot ^= (e&7)
__device__ __forceinline__ int uwT_off(int e, int s) {
    return e * 64 + ((((s >> 3) ^ (e & 7)) & 7) << 3) + (s & 7);
}
// SL: [64 t][64 s], slot ^= fSL(t)
__device__ __forceinline__ int fSL(int t) {
    return (((t & 3) << 1) ^ ((t >> 2) & 7)) & 7;
}
__device__ __forceinline__ int SL_off(int t, int s) {
    return t * 64 + ((((s >> 3) ^ fSL(t)) & 7) << 3) + (s & 7);
}

// Build the 4 A-fragments (K=128) of a rotary-transformed row in registers.
__device__ __forceinline__ void make_rot_frags(const float* __restrict__ G,
                                               size_t gb, float cv, float sv,
                                               int kgrp, short8* fr) {
    #pragma unroll
    for (int kk = 0; kk < 4; ++kk) {
        int d0 = kk * 32 + kgrp;
        int dl = d0 & 63;
        bool low = d0 < 64;
        float4 a1 = *(const float4*)(G + gb + dl);
        float4 b1 = *(const float4*)(G + gb + dl + 4);
        float4 a2 = *(const float4*)(G + gb + dl + 64);
        float4 b2 = *(const float4*)(G + gb + dl + 68);
        float v0, v1, v2, v3, v4, v5, v6, v7;
        if (low) {
            v0 = a1.x * cv - a2.x * sv; v1 = a1.y * cv - a2.y * sv;
            v2 = a1.z * cv - a2.z * sv; v3 = a1.w * cv - a2.w * sv;
            v4 = b1.x * cv - b2.x * sv; v5 = b1.y * cv - b2.y * sv;
            v6 = b1.z * cv - b2.z * sv; v7 = b1.w * cv - b2.w * sv;
        } else {
            v0 = a1.x * sv + a2.x * cv; v1 = a1.y * sv + a2.y * cv;
            v2 = a1.z * sv + a2.z * cv; v3 = a1.w * sv + a2.w * cv;
            v4 = b1.x * sv + b2.x * cv; v5 = b1.y * sv + b2.y * cv;
            v6 = b1.z * sv + b2.z * cv; v7 = b1.w * sv + b2.w * cv;
        }
        U8 r;
        r.u[0] = pkbf2(v0, v1); r.u[1] = pkbf2(v2, v3);
        r.u[2] = pkbf2(v4, v5); r.u[3] = pkbf2(v6, v7);
        fr[kk] = r.s;
    }
}

// ---------------------------------------------------------------------------
// K1: full-sequence inclusive prefix sum of dt over l, per (b,h).
// ---------------------------------------------------------------------------
__global__ __launch_bounds__(256) void k_scan_dt(const float* __restrict__ dt,
                                                 float* __restrict__ ang) {
    int bh = blockIdx.x;
    int b = bh / HH, h = bh % HH;
    int tid = threadIdx.x;
    const int PT = LL / 256;  // 16
    float v[PT];
    float s = 0.f;
    int tbase = tid * PT;
    for (int i = 0; i < PT; ++i) {
        v[i] = dt[(((size_t)b * LL + tbase + i) * HH) + h];
        s += v[i];
    }
    int lane = tid & 63, wv = tid >> 6;
    float ps = s;
    for (int off = 1; off < 64; off <<= 1) {
        float o = __shfl_up(ps, off, 64);
        if (lane >= off) ps += o;
    }
    __shared__ float wsum[4];
    if (lane == 63) wsum[wv] = ps;
    __syncthreads();
    float wadd = 0.f;
    for (int w = 0; w < wv; ++w) wadd += wsum[w];
    float run = wadd + ps - s;
    for (int i = 0; i < PT; ++i) {
        run += v[i];
        ang[(((size_t)b * LL + tbase + i) * HH) + h] = run;
    }
}

// ---------------------------------------------------------------------------
// K2: per-(b,n,h) intra-chunk tile. Round-5-proven structure; LDS = 40960 B
// (4 blocks/CU). No shared float arrays (per-thread recompute from L1-hot
// ang/dt). SL aliases rkS after phase 1, fenced by barriers on both sides.
// ---------------------------------------------------------------------------
__global__ __launch_bounds__(256, 4) void k_intra(
    const float* __restrict__ x, const float* __restrict__ dt,
    const float* __restrict__ A, const float* __restrict__ Bg,
    const float* __restrict__ Cg, const float* __restrict__ ang,
    const float* __restrict__ Dd,
    float* __restrict__ out, ushort* __restrict__ dH,
    float* __restrict__ cdecay) {
    int n = blockIdx.x, h = blockIdx.y, b = blockIdx.z;
    int tid = threadIdx.x;
    int t0 = n * CC;

    __shared__ ushort rkS[CC * DQK];    // 16384 B; first 8192 B alias SL later
    __shared__ ushort rkT[DQK * CC];    // 16384 B
    __shared__ ushort uwT[DV * CC];     // 8192 B
    // total 40960 B -> exactly 4 blocks/CU

    int wv = tid >> 6, lane = tid & 63;
    int lrow = lane & 15;
    int g = lane >> 4;
    int kgrp = g * 8;
    int orow = g * 4;

    float Ah = A[h];
    size_t angBase = ((size_t)b * LL + t0) * HH + h;  // ang[t] at angBase + t*HH
    float aend = ang[angBase + 63 * HH];

    if (tid == 0) {
        float angPrev = (t0 == 0) ? 0.f : ang[angBase - HH];
        cdecay[(b * NN + n) * HH + h] = __expf(Ah * (aend - angPrev));
    }

    const float* BgRow = Bg + ((size_t)b * LL + t0) * DQK;  // row s stride 128

    // ---- stage rkS (swizzled [s][d], b128 writes); per-thread sincos ----
    #pragma unroll
    for (int it = 0; it < 2; ++it) {
        int w = tid + 256 * it;          // 0..511
        int s = w >> 3, oct = w & 7;
        float a = ang[angBase + (size_t)s * HH];
        float sv, cv;
        __sincosf(a, &sv, &cv);
        const float* p = BgRow + s * DQK + 8 * oct;
        float4 a0 = *(const float4*)(p);
        float4 a1 = *(const float4*)(p + 4);
        float4 b0 = *(const float4*)(p + 64);
        float4 b1 = *(const float4*)(p + 68);
        U8 lo, hi;
        lo.u[0] = pkbf2(a0.x * cv - b0.x * sv, a0.y * cv - b0.y * sv);
        lo.u[1] = pkbf2(a0.z * cv - b0.z * sv, a0.w * cv - b0.w * sv);
        lo.u[2] = pkbf2(a1.x * cv - b1.x * sv, a1.y * cv - b1.y * sv);
        lo.u[3] = pkbf2(a1.z * cv - b1.z * sv, a1.w * cv - b1.w * sv);
        hi.u[0] = pkbf2(a0.x * sv + b0.x * cv, a0.y * sv + b0.y * cv);
        hi.u[1] = pkbf2(a0.z * sv + b0.z * cv, a0.w * sv + b0.w * cv);
        hi.u[2] = pkbf2(a1.x * sv + b1.x * cv, a1.y * sv + b1.y * cv);
        hi.u[3] = pkbf2(a1.z * sv + b1.z * cv, a1.w * sv + b1.w * cv);
        *(short8*)&rkS[rk_off(s, 8 * oct)] = lo.s;
        *(short8*)&rkS[rk_off(s, 8 * oct + 64)] = hi.s;
    }

    // ---- stage uwT = dt*x*decay_to_end, [e][s]; per-thread dw recompute ----
    #pragma unroll
    for (int it = 0; it < 2; ++it) {
        int w = tid + 256 * it;          // 0..511
        int e = w & 63;
        int s0 = 8 * (w >> 6);
        U8 pk;
        #pragma unroll
        for (int jp = 0; jp < 4; ++jp) {
            int s_a = s0 + 2 * jp, s_b = s_a + 1;
            float dwA = dt[(((size_t)b * LL + t0 + s_a) * HH) + h] *
                        __expf(Ah * (aend - ang[angBase + (size_t)s_a * HH]));
            float dwB = dt[(((size_t)b * LL + t0 + s_b) * HH) + h] *
                        __expf(Ah * (aend - ang[angBase + (size_t)s_b * HH]));
            float xa = x[((((size_t)b * LL + t0 + s_a) * HH) + h) * DV + e] * dwA;
            float xb = x[((((size_t)b * LL + t0 + s_b) * HH) + h) * DV + e] * dwB;
            pk.u[jp] = pkbf2(xa, xb);
        }
        *(short8*)&uwT[uwT_off(e, s0)] = pk.s;
    }

    // ---- rq A-fragments in registers; per-lane trig for own t ----
    int t_own = 16 * wv + lrow;
    float a_town = ang[angBase + (size_t)t_own * HH];
    float cvq, svq;
    __sincosf(a_town, &svq, &cvq);
    short8 aq[4];
    make_rot_frags(Cg, ((size_t)b * LL + t0 + t_own) * DQK, cvq, svq, kgrp, aq);

    __syncthreads();  // BARRIER A: rkS + uwT staged

    // ---- build rkT from rkS (transposed scalar reads -> b128 write) ----
    #pragma unroll
    for (int it = 0; it < 4; ++it) {
        int w = tid + 256 * it;          // 0..1023
        int d = w & 127, soct = w >> 7;
        int s0 = 8 * soct;
        uint v[8];
        #pragma unroll
        for (int j = 0; j < 8; ++j) v[j] = rkS[rk_off(s0 + j, d)];
        U8 pk;
        pk.u[0] = v[0] | (v[1] << 16);
        pk.u[1] = v[2] | (v[3] << 16);
        pk.u[2] = v[4] | (v[5] << 16);
        pk.u[3] = v[6] | (v[7] << 16);
        *(short8*)&rkT[rkT_off(d, s0)] = pk.s;
    }

    // ---- Phase 1: S = rq . rk^T (m = t-rows of wave, n = s, K = 128) ----
    f32x4 accS[4] = {{0.f,0.f,0.f,0.f},{0.f,0.f,0.f,0.f},
                     {0.f,0.f,0.f,0.f},{0.f,0.f,0.f,0.f}};
    #pragma unroll
    for (int kk = 0; kk < 4; ++kk) {
        #pragma unroll
        for (int nt = 0; nt < 4; ++nt) {
            int s = 16 * nt + lrow;
            const short8 bfr = *(const short8*)&rkS[rk_off(s, 32 * kk + kgrp)];
            accS[nt] = __builtin_amdgcn_mfma_f32_16x16x32_bf16(
                aq[kk], bfr, accS[nt], 0, 0, 0);
        }
    }

    __syncthreads();  // BARRIER B: rkT visible; all rkS reads complete

    // ---- SL = mask(t>=s) * S * exp(Ah*(ang_t - aend)), into rkS alias ----
    ushort* SLs = rkS;  // first 4096 ushorts of the dead rkS buffer
    #pragma unroll
    for (int rr = 0; rr < 4; ++rr) {
        int t = 16 * wv + orow + rr;
        float etv = __expf(Ah * (ang[angBase + (size_t)t * HH] - aend));
        #pragma unroll
        for (int nt = 0; nt < 4; ++nt) {
            int s = 16 * nt + lrow;
            float v = (t >= s) ? accS[nt][rr] * etv : 0.f;
            SLs[SL_off(t, s)] = f2bf(v);
        }
    }

    __syncthreads();  // BARRIER C: SL visible

    // ---- Phase 2: y_intra = SL . uwT^T ; out = 4*y + D*x ----
    {
        f32x4 accY[4] = {{0.f,0.f,0.f,0.f},{0.f,0.f,0.f,0.f},
                         {0.f,0.f,0.f,0.f},{0.f,0.f,0.f,0.f}};
        #pragma unroll
        for (int kk = 0; kk < 2; ++kk) {
            const short8 a = *(const short8*)&SLs[SL_off(16 * wv + lrow, 32 * kk + kgrp)];
            #pragma unroll
            for (int nt = 0; nt < 4; ++nt) {
                const short8 bfr = *(const short8*)&uwT[uwT_off(16 * nt + lrow, 32 * kk + kgrp)];
                accY[nt] = __builtin_amdgcn_mfma_f32_16x16x32_bf16(
                    a, bfr, accY[nt], 0, 0, 0);
            }
        }
        float Dh = Dd[h];
        #pragma unroll
        for (int nt = 0; nt < 4; ++nt) {
            int e = 16 * nt + lrow;
            #pragma unroll
            for (int rr = 0; rr < 4; ++rr) {
                int t = 16 * wv + orow + rr;
                size_t oidx = ((((size_t)b * LL + t0 + t) * HH) + h) * DV + e;
                out[oidx] = MIMO_RANK * accY[nt][rr] + Dh * x[oidx];
            }
        }
    }

    // ---- Phase 3: dH = rkT . uwT^T (m = d, n = e, K = 64) ----
    {
        f32x4 accH[2][4] = {{{0.f,0.f,0.f,0.f},{0.f,0.f,0.f,0.f},
                             {0.f,0.f,0.f,0.f},{0.f,0.f,0.f,0.f}},
                            {{0.f,0.f,0.f,0.f},{0.f,0.f,0.f,0.f},
                             {0.f,0.f,0.f,0.f},{0.f,0.f,0.f,0.f}}};
        #pragma unroll
        for (int kk = 0; kk < 2; ++kk) {
            #pragma unroll
            for (int mt = 0; mt < 2; ++mt) {
                const short8 a = *(const short8*)&rkT[rkT_off(32 * wv + 16 * mt + lrow, 32 * kk + kgrp)];
                #pragma unroll
                for (int nt = 0; nt < 4; ++nt) {
                    const short8 bfr = *(const short8*)&uwT[uwT_off(16 * nt + lrow, 32 * kk + kgrp)];
                    accH[mt][nt] = __builtin_amdgcn_mfma_f32_16x16x32_bf16(
                        a, bfr, accH[mt][nt], 0, 0, 0);
                }
            }
        }
        // direct permuted global store: 16B per lane per q, fully coalesced
        ushort* dHp = dH + (((size_t)(b * NN + n) * HH) + h) * (DQK * DV);
        #pragma unroll
        for (int q = 0; q < 4; ++q) {
            int mt = q >> 1, np = q & 1;
            U8 st;
            st.u[0] = pkbf2(accH[mt][2 * np][0], accH[mt][2 * np][1]);
            st.u[1] = pkbf2(accH[mt][2 * np][2], accH[mt][2 * np][3]);
            st.u[2] = pkbf2(accH[mt][2 * np + 1][0], accH[mt][2 * np + 1][1]);
            st.u[3] = pkbf2(accH[mt][2 * np + 1][2], accH[mt][2 * np + 1][3]);
            *(short8*)(dHp + ((size_t)(wv * 4 + q) * 64 + lane) * 8) = st.s;
        }
    }
}

// ---------------------------------------------------------------------------
// K3: sequential chunk scan, in place, bf16 pairs, f32 accumulators.
// ---------------------------------------------------------------------------
__global__ __launch_bounds__(256) void k_scan_chunks(
    uint* __restrict__ dH, const float* __restrict__ cdecay) {
    uint f = blockIdx.x * 256 + threadIdx.x;   // 0..262143
    int b = (int)(f >> 17);
    uint r = f & 0x1FFFF;
    int h = (int)((r >> 12) & 31);
    uint base = ((uint)b << 23) | r;
    const float* cd = cdecay + (size_t)b * NN * HH + h;
    float h0 = 0.f, h1 = 0.f;
    for (int n = 0; n < NN; ++n) {
        uint a = base + ((uint)n << 17);
        uint v = dH[a];
        float v0 = bfbits2f(v & 0xFFFF), v1 = bfbits2f(v >> 16);
        dH[a] = pkbf2(h0, h1);       // Hprev for chunk n
        float c = cd[n * HH];
        h0 = c * h0 + v0;
        h1 = c * h1 + v1;
    }
}

// ---------------------------------------------------------------------------
// K4: y_inter + final combine (round-5-proven, unchanged).
// ---------------------------------------------------------------------------
__global__ __launch_bounds__(256, 4) void k_inter(
    const float* __restrict__ A, const float* __restrict__ Cg,
    const float* __restrict__ ang, const ushort* __restrict__ Hprev,
    float* __restrict__ out) {
    int n = blockIdx.x, h = blockIdx.y, b = blockIdx.z;
    int tid = threadIdx.x;
    int t0 = n * CC;

    __shared__ __align__(16) uint Hp[16 * 260];  // rows 16B-aligned
    __shared__ float csv[CC], ssv[CC], gs[CC], angs[CC];
    __shared__ float angPrev_s;

    float Ah = A[h];
    if (tid < CC) {
        float a = ang[(((size_t)b * LL + t0 + tid) * HH) + h];
        angs[tid] = a;
        float sv, cv;
        __sincosf(a, &sv, &cv);
        csv[tid] = cv;
        ssv[tid] = sv;
    }
    if (tid == 0)
        angPrev_s = (t0 == 0) ? 0.f : ang[(((size_t)b * LL + t0 - 1) * HH) + h];
    __syncthreads();
    if (tid < CC) gs[tid] = __expf(Ah * (angs[tid] - angPrev_s));

    const uint* Hsrc = (const uint*)(Hprev + (((size_t)(b * NN + n) * HH) + h) * (DQK * DV));
    #pragma unroll
    for (int it = 0; it < 4; ++it) {
        int p = tid + 256 * it;          // 0..1023 (uint4 index)
        uint4 v = *(const uint4*)(Hsrc + (size_t)p * 4);
        int row = p >> 6, c = p & 63;
        uint4* Hrow = (uint4*)&Hp[row * 260];
        Hrow[c] = v;
    }

    int wv = tid >> 6, lane = tid & 63;
    int lrow = lane & 15;
    int g2 = lane >> 4;
    int kgrp = g2 * 8;
    int orow = g2 * 4;

    int t_own = 16 * wv + lrow;
    short8 aq[4];
    make_rot_frags(Cg, ((size_t)b * LL + t0 + t_own) * DQK,
                   csv[t_own], ssv[t_own], kgrp, aq);
    __syncthreads();

    f32x4 accI[4] = {{0.f,0.f,0.f,0.f},{0.f,0.f,0.f,0.f},
                     {0.f,0.f,0.f,0.f},{0.f,0.f,0.f,0.f}};
    int mt = g2 >> 1;
    int gp0 = 2 * (g2 & 1);
    #pragma unroll
    for (int kk = 0; kk < 4; ++kk) {
        #pragma unroll
        for (int nt = 0; nt < 4; ++nt) {
            int q = mt * 2 + (nt >> 1);
            int row = kk * 4 + q;
            int sb = (nt & 1) * 2;
            const uint2 u0 = *(const uint2*)&Hp[row * 260 + (16 * gp0 + lrow) * 4 + sb];
            const uint2 u1 = *(const uint2*)&Hp[row * 260 + (16 * (gp0 + 1) + lrow) * 4 + sb];
            U8 fr;
            fr.u[0] = u0.x; fr.u[1] = u0.y; fr.u[2] = u1.x; fr.u[3] = u1.y;
            accI[nt] = __builtin_amdgcn_mfma_f32_16x16x32_bf16(
                aq[kk], fr.s, accI[nt], 0, 0, 0);
        }
    }

    #pragma unroll
    for (int rr = 0; rr < 4; ++rr) {
        int t = 16 * wv + orow + rr;
        float g4 = MIMO_RANK * gs[t];
        #pragma unroll
        for (int nt = 0; nt < 4; ++nt) {
            int e = 16 * nt + lrow;
            size_t oidx = ((((size_t)b * LL + t0 + t) * HH) + h) * DV + e;
            out[oidx] += g4 * accI[nt][rr];
        }
    }
}

// ---------------------------------------------------------------------------
extern "C" void kernel_launch(void* const* d_in, const int* in_sizes, int n_in,
                              void* d_out, int out_size, void* d_ws,
                              size_t ws_size, hipStream_t stream) {
    (void)in_sizes; (void)n_in; (void)out_size; (void)ws_size;
    const float* x  = (const float*)d_in[0];
    const float* dt = (const float*)d_in[1];
    const float* A  = (const float*)d_in[2];
    const float* Bg = (const float*)d_in[3];
    const float* Cg = (const float*)d_in[4];
    const float* Dd = (const float*)d_in[5];
    float* out = (float*)d_out;
    float* ws  = (float*)d_ws;

    float*  ang    = ws;                       // B*L*H       = 262144 f32
    float*  cdecay = ws + 262144;              // B*N*H       = 4096 f32
    ushort* dH     = (ushort*)(ws + 266240);   // B*N*H*DQK*DV bf16 (67 MB)

    k_scan_dt<<<BB * HH, 256, 0, stream>>>(dt, ang);
    k_intra<<<dim3(NN, HH, BB), 256, 0, stream>>>(x, dt, A, Bg, Cg, ang, Dd,
                                                  out, dH, cdecay);
    k_scan_chunks<<<(BB * HH * DQK * DV / 2) / 256, 256, 0, stream>>>(
        (uint*)dH, cdecay);
    k_inter<<<dim3(NN, HH, BB), 256, 0, stream>>>(A, Cg, ang, dH, out);
}